// Round 7
// baseline (69.572 us; speedup 1.0000x reference)
//
#include <hip/hip_runtime.h>
#include <hip/hip_bf16.h>
#include <math.h>

// TokenCompressor: B=8, N=16384, C=128, BLOCK=32, STRIDE=16 -> nb=1023
// Decomposition: chunks c of 16 tokens; A = x.view(8192, 2048) (contiguous!)
//   P[m, 0:256]  = chunk[m] @ W1[0:2048]
//   P[m, 256:512]= chunk[m] @ W1[2048:4096]
//   h[j] = gelu(P[j,0:256] + P[j+1,256:512] + b1 + posflat@W1)
//   out[j] = h[j] @ W2 + b2
// R7: R1-R6 all ~310 TF; perf tracks blocks/CU x cache traffic, not loop
// structure. Fix both: pre-convert X to bf16 (k_xcvt) -> A traffic halves
// and LDS/buffer halves (16 KB at BK=32) -> 3 buffers, 3 blocks/CU, m97
// recipe (gload_lds both operands, 8 ds_read : 16 MFMA, counted vmcnt(8)).
// Also fixed 4-way bank conflict: swizzle is chunk ^ ((row>>1)&3).

typedef __attribute__((ext_vector_type(8))) short short8;
typedef __attribute__((ext_vector_type(4))) float f4;

#define OFF_BT   0u                          // 512x2048 bf16 = 2 MB
#define OFF_W2T  (2u << 20)                  // 128x256 bf16 = 64 KB
#define OFF_PART ((2u << 20) + (64u << 10))  // 64x256 f32 = 64 KB
#define OFF_BIAS ((2u << 20) + (128u << 10)) // 256 f32
#define OFF_P    (4u << 20)                  // 4 x (8192x512) bf16 = 32 MB
#define OFF_XB   (36u << 20)                 // 8192x2048 bf16 = 33.6 MB

static __device__ __forceinline__ unsigned short f2bf(float f) {
  union { float f; unsigned u; } v; v.f = f;
  return (unsigned short)((v.u + 0x7FFFu + ((v.u >> 16) & 1u)) >> 16);
}
static __device__ __forceinline__ float bf2f(unsigned short h) {
  union { unsigned u; float f; } v; v.u = ((unsigned)h) << 16;
  return v.f;
}
static __device__ __forceinline__ void gload_lds16(const void* g, void* l) {
  __builtin_amdgcn_global_load_lds(
      (const __attribute__((address_space(1))) void*)g,
      (__attribute__((address_space(3))) void*)l, 16, 0, 0);
}

// ---- k_xcvt: X f32 -> Xb bf16 (flat copy, 32 elems/thread) --------------
__global__ __launch_bounds__(256) void k_xcvt(const float* __restrict__ X,
                                              unsigned short* __restrict__ Xb) {
  const size_t t = (size_t)blockIdx.x * 256 + threadIdx.x;
  const float* src = X + t * 32;
  unsigned short* dst = Xb + t * 32;
#pragma unroll
  for (int i = 0; i < 4; ++i) {
    f4 a = *(const f4*)(src + i * 8);
    f4 b = *(const f4*)(src + i * 8 + 4);
    union { short8 s; unsigned u[4]; } pk;
    asm("v_cvt_pk_bf16_f32 %0, %1, %2" : "=v"(pk.u[0]) : "v"(a[0]), "v"(a[1]));
    asm("v_cvt_pk_bf16_f32 %0, %1, %2" : "=v"(pk.u[1]) : "v"(a[2]), "v"(a[3]));
    asm("v_cvt_pk_bf16_f32 %0, %1, %2" : "=v"(pk.u[2]) : "v"(b[0]), "v"(b[1]));
    asm("v_cvt_pk_bf16_f32 %0, %1, %2" : "=v"(pk.u[3]) : "v"(b[2]), "v"(b[3]));
    *(short8*)(dst + i * 8) = pk.s;
  }
}

// ---- k_prep: blocks 0..255: W1 -> Bt (512x2048 bf16, n-major) + bias parts
//              blocks 256..383: W2 (256x128 f32) -> W2t (128x256 bf16, T)
__global__ __launch_bounds__(256) void k_prep(const float* __restrict__ W1,
                                              const float* __restrict__ pos,
                                              const float* __restrict__ W2,
                                              unsigned short* __restrict__ Bt,
                                              unsigned short* __restrict__ W2t,
                                              float* __restrict__ part) {
  __shared__ float T[64][65];
  const int w = blockIdx.x;
  const int t = threadIdx.x;
  if (w >= 256) {
    const int n = w - 256;
    W2t[n * 256 + t] = f2bf(W2[t * 128 + n]);
    return;
  }
  const int h = w >> 7, rem = w & 127, kt = rem >> 2, nt = rem & 3;
  const int krow0 = h * 2048 + kt * 64, col0 = nt * 64;
  const int lr = t >> 2, lc = (t & 3) * 16;
  const float* src = W1 + (size_t)(krow0 + lr) * 256 + col0 + lc;
#pragma unroll
  for (int i = 0; i < 4; ++i) {
    f4 v = *(const f4*)(src + i * 4);
#pragma unroll
    for (int q = 0; q < 4; ++q) T[lr][lc + i * 4 + q] = v[q];
  }
  __syncthreads();
  if (t < 64) {
    float s = 0.f;
#pragma unroll 8
    for (int k = 0; k < 64; ++k) s += T[k][t] * pos[krow0 + k];
    part[(h * 32 + kt) * 256 + col0 + t] = s;
  }
  const int nl = t >> 2, kc = (t & 3) * 16;
  short8 o0, o1;
#pragma unroll
  for (int i = 0; i < 8; ++i) o0[i] = (short)f2bf(T[kc + i][nl]);
#pragma unroll
  for (int i = 0; i < 8; ++i) o1[i] = (short)f2bf(T[kc + 8 + i][nl]);
  unsigned short* dst = Bt + (size_t)(256 * h + col0 + nl) * 2048 + kt * 64 + kc;
  *(short8*)dst = o0;
  *(short8*)(dst + 8) = o1;
}

// ---- k_bias ------------------------------------------------------------
__global__ __launch_bounds__(256) void k_bias(const float* __restrict__ b1,
                                              const float* __restrict__ part,
                                              float* __restrict__ bias) {
  int n = threadIdx.x;
  float s = b1[n];
#pragma unroll 8
  for (int g = 0; g < 64; ++g) s += part[g * 256 + n];
  bias[n] = s;
}

// ---- k_gemm: Ppart[ks] (8192x512 bf16) = Xb[:,ks*512:+512] @ Bt^T -------
// 128x128 tile, BK=32, 16 steps. 4 waves x (64x64). 1024 wgs, 3 blocks/CU.
// Both operands bf16 via global_load_lds (4 instr/wave/tile), 3-deep
// pipeline, counted vmcnt(8). Swizzle: 16B slot = chunk ^ ((row>>1)&3)
// (2 lanes/bank on ds_read_b128 = free).
__global__ __launch_bounds__(256, 3) void k_gemm(const unsigned short* __restrict__ Xb,
                                                 const unsigned short* __restrict__ Bt,
                                                 unsigned short* __restrict__ P) {
  __shared__ __align__(16) char lds[3][16384];  // per buf: A 8K | B 8K
  const int orig = blockIdx.x;
  const int wg = (orig & 7) * 128 + (orig >> 3);  // bijective (1024%8==0)
  const int mt = wg >> 4;                 // 0..63 (XCD keeps mt-band)
  const int nt = (wg >> 2) & 3;           // 0..3
  const int ks_split = wg & 3;            // 0..3
  const int m0 = mt * 128, n0 = nt * 128;
  const int k0 = ks_split * 512;
  const int t = threadIdx.x;
  const int wid = t >> 6, lane = t & 63;
  const int wm = (wid >> 1) * 64, wn = (wid & 1) * 64;

  f4 acc[4][4];
#pragma unroll
  for (int i = 0; i < 4; ++i)
#pragma unroll
    for (int j = 0; j < 4; ++j) acc[i][j] = f4{0.f, 0.f, 0.f, 0.f};

  // per tile: 2 A + 2 B gload_lds per wave. Wave-instr (ii, wid) covers
  // rows [ii*64+wid*16, +16). lane -> row += lane>>2, slot = lane&3,
  // source chunk = (lane&3) ^ ((row>>1)&3).
#define ISSUE(BUF, KT)                                                     \
  do {                                                                     \
    const int kbase = k0 + (KT) * 32;                                      \
    _Pragma("unroll") for (int ii = 0; ii < 2; ++ii) {                     \
      const int row = ii * 64 + wid * 16 + (lane >> 2);                    \
      const int ch = (lane & 3) ^ ((row >> 1) & 3);                        \
      const unsigned short* srcA =                                         \
          Xb + (size_t)(m0 + row) * 2048 + kbase + ch * 8;                 \
      gload_lds16(srcA, &lds[BUF][ii * 4096 + wid * 1024]);                \
      const unsigned short* srcB =                                         \
          Bt + (size_t)(n0 + row) * 2048 + kbase + ch * 8;                 \
      gload_lds16(srcB, &lds[BUF][8192 + ii * 4096 + wid * 1024]);         \
    }                                                                      \
  } while (0)

#define COMPUTE(BUF)                                                       \
  do {                                                                     \
    const unsigned short* Ab = (const unsigned short*)&lds[BUF][0];        \
    const unsigned short* Bb = (const unsigned short*)&lds[BUF][8192];     \
    short8 af[4], bfv[4];                                                  \
    const int cA = lane >> 4;                                              \
    _Pragma("unroll") for (int f = 0; f < 4; ++f) {                        \
      const int rowA = wm + f * 16 + (lane & 15);                          \
      af[f] = *(const short8*)(Ab + rowA * 32 +                            \
                               ((cA ^ ((rowA >> 1) & 3)) << 3));           \
      const int rowB = wn + f * 16 + (lane & 15);                          \
      bfv[f] = *(const short8*)(Bb + rowB * 32 +                           \
                                ((cA ^ ((rowB >> 1) & 3)) << 3));          \
    }                                                                      \
    __builtin_amdgcn_s_setprio(1);                                         \
    _Pragma("unroll") for (int i2 = 0; i2 < 4; ++i2)                       \
        _Pragma("unroll") for (int j2 = 0; j2 < 4; ++j2)                   \
        acc[i2][j2] = __builtin_amdgcn_mfma_f32_16x16x32_bf16(             \
            af[i2], bfv[j2], acc[i2][j2], 0, 0, 0);                        \
    __builtin_amdgcn_s_setprio(0);                                         \
  } while (0)

  // prologue: 3 tiles in flight (12 instr); wait tile 0 (leave 8)
  ISSUE(0, 0);
  ISSUE(1, 1);
  ISSUE(2, 2);
  __builtin_amdgcn_sched_barrier(0);
  asm volatile("s_waitcnt vmcnt(8)" ::: "memory");
  __builtin_amdgcn_s_barrier();
  __builtin_amdgcn_sched_barrier(0);

#pragma unroll
  for (int kt = 0; kt < 16; ++kt) {
    COMPUTE(kt % 3);
    __builtin_amdgcn_s_barrier();          // all waves done reading buf
    __builtin_amdgcn_sched_barrier(0);
    if (kt + 3 < 16) ISSUE(kt % 3, kt + 3);
    if (kt < 15) {
      __builtin_amdgcn_sched_barrier(0);
      if (kt < 13)       asm volatile("s_waitcnt vmcnt(8)" ::: "memory");
      else if (kt == 13) asm volatile("s_waitcnt vmcnt(4)" ::: "memory");
      else               asm volatile("s_waitcnt vmcnt(0)" ::: "memory");
      __builtin_amdgcn_s_barrier();
      __builtin_amdgcn_sched_barrier(0);
    }
  }
#undef ISSUE
#undef COMPUTE

  // epilogue: partial write. C/D layout: col=lane&15, row=(lane>>4)*4+reg
  unsigned short* Pp = P + (size_t)ks_split * (8192 * 512);
  const int mb = m0 + wm, nb = n0 + wn;
#pragma unroll
  for (int i = 0; i < 4; ++i)
#pragma unroll
    for (int j = 0; j < 4; ++j) {
      const int row0 = mb + i * 16 + ((lane >> 4) << 2);
      const int col = nb + j * 16 + (lane & 15);
#pragma unroll
      for (int r = 0; r < 4; ++r)
        Pp[(size_t)(row0 + r) * 512 + col] = f2bf(acc[i][j][r]);
    }
}

// ---- k_comb: h=gelu(sum_ks(P0,P1)+bias); out = h@W2 + b2 ---------------
__global__ __launch_bounds__(256) void k_comb(const unsigned short* __restrict__ P,
                                              const unsigned short* __restrict__ W2t,
                                              const float* __restrict__ bias,
                                              const float* __restrict__ b2,
                                              float* __restrict__ out) {
  __shared__ unsigned short W2s[128 * 256];
  __shared__ unsigned short Hs[32 * 256];
  const int wg = blockIdx.x;
  const int b = wg >> 5, jt = wg & 31;
  const int j0 = jt * 32;
  const int t = threadIdx.x;

  {  // stage W2t
    const int row = t >> 1, halfc = (t & 1) * 128;
    const unsigned short* src = W2t + row * 256 + halfc;
    const int cbw = halfc >> 3;
#pragma unroll
    for (int i = 0; i < 16; ++i) {
      short8 v = *(const short8*)(src + i * 8);
      const int c = (cbw + i) ^ (row & 7);
      *(short8*)&W2s[row * 256 + c * 8] = v;
    }
  }
  {  // h rows
    const int r = t >> 3, seg = t & 7;
    const int j = j0 + r;
    const size_t m = (size_t)b * 1024 + j;
    const size_t mp1 = (j < 1023) ? m + 1 : m;
    const float* bs = bias + seg * 32;
    const int cbh = seg * 4;
#pragma unroll
    for (int i = 0; i < 4; ++i) {
      float f0[8];
#pragma unroll
      for (int q = 0; q < 8; ++q) f0[q] = bs[i * 8 + q];
#pragma unroll
      for (int ksp = 0; ksp < 4; ++ksp) {
        const unsigned short* Pk = P + (size_t)ksp * (8192 * 512);
        short8 v0 = *(const short8*)(Pk + m * 512 + seg * 32 + i * 8);
        short8 v1 = *(const short8*)(Pk + mp1 * 512 + 256 + seg * 32 + i * 8);
#pragma unroll
        for (int q = 0; q < 8; ++q)
          f0[q] += bf2f((unsigned short)v0[q]) + bf2f((unsigned short)v1[q]);
      }
      short8 pk;
#pragma unroll
      for (int q = 0; q < 8; ++q) {
        float g = 0.5f * f0[q] * (1.f + erff(f0[q] * 0.70710678118f));
        pk[q] = (short)f2bf(g);
      }
      const int c = (cbh + i) ^ (r & 7);
      *(short8*)&Hs[r * 256 + c * 8] = pk;
    }
  }
  __syncthreads();

  const int wid = t >> 6, lane = t & 63;
  f4 acc[2][2];
#pragma unroll
  for (int i = 0; i < 2; ++i)
#pragma unroll
    for (int j = 0; j < 2; ++j) acc[i][j] = f4{0.f, 0.f, 0.f, 0.f};

#pragma unroll
  for (int ks = 0; ks < 8; ++ks) {
    short8 af[2], bfr[2];
    const int cc = ks * 4 + (lane >> 4);
#pragma unroll
    for (int f = 0; f < 2; ++f) {
      const int ra = f * 16 + (lane & 15);
      af[f] = *(const short8*)&Hs[ra * 256 + ((cc ^ (ra & 7)) << 3)];
      const int rb = wid * 32 + f * 16 + (lane & 15);
      bfr[f] = *(const short8*)&W2s[rb * 256 + ((cc ^ (rb & 7)) << 3)];
    }
#pragma unroll
    for (int i = 0; i < 2; ++i)
#pragma unroll
      for (int j = 0; j < 2; ++j)
        acc[i][j] = __builtin_amdgcn_mfma_f32_16x16x32_bf16(af[i], bfr[j],
                                                            acc[i][j], 0, 0, 0);
  }
#pragma unroll
  for (int i = 0; i < 2; ++i)
#pragma unroll
    for (int j = 0; j < 2; ++j) {
      const int row0 = i * 16 + ((lane >> 4) << 2);
      const int col = wid * 32 + j * 16 + (lane & 15);
      const float bb = b2[col];
#pragma unroll
      for (int r = 0; r < 4; ++r) {
        const int jj = j0 + row0 + r;
        if (jj < 1023)
          out[((size_t)b * 1023 + jj) * 128 + col] = acc[i][j][r] + bb;
      }
    }
}

extern "C" void kernel_launch(void* const* d_in, const int* in_sizes, int n_in,
                              void* d_out, int out_size, void* d_ws, size_t ws_size,
                              hipStream_t stream) {
  const float* x   = (const float*)d_in[0];
  const float* pos = (const float*)d_in[1];
  const float* W1  = (const float*)d_in[2];
  const float* b1  = (const float*)d_in[3];
  const float* W2  = (const float*)d_in[4];
  const float* b2  = (const float*)d_in[5];
  float* out = (float*)d_out;
  char* ws = (char*)d_ws;
  unsigned short* Bt  = (unsigned short*)(ws + OFF_BT);
  unsigned short* W2t = (unsigned short*)(ws + OFF_W2T);
  float* part         = (float*)(ws + OFF_PART);
  float* bias         = (float*)(ws + OFF_BIAS);
  unsigned short* P   = (unsigned short*)(ws + OFF_P);
  unsigned short* Xb  = (unsigned short*)(ws + OFF_XB);

  k_xcvt<<<2048, 256, 0, stream>>>(x, Xb);
  k_prep<<<384, 256, 0, stream>>>(W1, pos, W2, Bt, W2t, part);
  k_bias<<<1, 256, 0, stream>>>(b1, part, bias);
  k_gemm<<<1024, 256, 0, stream>>>(Xb, Bt, P);
  k_comb<<<256, 256, 0, stream>>>(P, W2t, bias, b2, out);
}